// Round 10
// baseline (62.549 us; speedup 1.0000x reference)
//
#include <hip/hip_runtime.h>
#include <hip/hip_bf16.h>

#define SEQ 1024

typedef __attribute__((ext_vector_type(8))) short s16x8;
typedef __attribute__((ext_vector_type(4))) float f32x4;
typedef __attribute__((ext_vector_type(2))) unsigned int u32x2;
typedef __attribute__((ext_vector_type(4))) unsigned int u32x4;
typedef __attribute__((ext_vector_type(2))) float f32x2;

// bf16 element offsets in workspace
//  P01[v0][v1][512] = b1 + G0[v0] + G1[v1]   (v=38 is the zero/pad row)
//  G2 [v][512]
//  P34[v3][v4][512] = G3[v3] + G4[v4]
#define P01P 0
#define G2P  (1521 * 512)
#define P34P (G2P + 39 * 512)
#define W2P  (P34P + 1521 * 512)
#define W3P  (W2P + 256 * 512)
#define W4P  (W3P + 64 * 512)
#define BF_END (W4P + 12 * 512)
// fp32 G scratch (5*39*512 floats) after the bf16 region

#define F2 (16 * 16)
#define F3 (8 * 8)
#define F4 (3 * 4)
#define FTOT (F2 + F3 + F4)

__device__ __forceinline__ unsigned int f2bf(float f) {
    unsigned int u = __float_as_uint(f);
    return (u + 0x7fffu + ((u >> 16) & 1u)) >> 16;   // RNE
}

__device__ __forceinline__ unsigned short bfbits(float f) {
    __hip_bfloat16 h = __float2bfloat16(f);
    unsigned short u;
    __builtin_memcpy(&u, &h, 2);
    return u;
}

__device__ __forceinline__ unsigned pk2(float a, float b) {
    return (unsigned)bfbits(a) | ((unsigned)bfbits(b) << 16);
}

__device__ __forceinline__ float bf2f(short x) {
    return __uint_as_float(((unsigned)(unsigned short)x) << 16);
}

// prep1: blocks [0,195) -> fp32 GF[j][v][o]; blocks [195,..) pack W2/3/4 MFMA frags
__global__ void prep1(const float* __restrict__ w1, const float* __restrict__ w2,
                      const float* __restrict__ w3, const float* __restrict__ w4,
                      const float* __restrict__ emb, unsigned short* __restrict__ dst) {
    if (blockIdx.x < 195) {
        float* gf = reinterpret_cast<float*>(dst + BF_END);
        const int j = blockIdx.x / 39;
        const int v = blockIdx.x % 39;
        const int o = threadIdx.x;
        if (v >= 38) { gf[(j * 39 + v) * 512 + o] = 0.f; return; }
        __shared__ float ev[128];
        if (threadIdx.x < 128) ev[threadIdx.x] = emb[v * 128 + threadIdx.x];
        __syncthreads();
        const float* wr = w1 + o * 640 + j * 128;
        float s = 0.f;
        #pragma unroll
        for (int e = 0; e < 128; e += 4) {
            const float4 a = *reinterpret_cast<const float4*>(wr + e);
            s += a.x * ev[e] + a.y * ev[e + 1] + a.z * ev[e + 2] + a.w * ev[e + 3];
        }
        gf[(j * 39 + v) * 512 + o] = s;
    } else {
        const int g = (blockIdx.x - 195) * 512 + threadIdx.x;
        if (g >= FTOT * 64) return;
        const int lane = g & 63;
        const int t    = g >> 6;
        const float* w; int K, N, KC, base, tl;
        if (t < F2)           { w = w2; K = 512; N = 256; KC = 16; base = W2P; tl = t; }
        else if (t < F2 + F3) { w = w3; K = 256; N = 128; KC = 8;  base = W3P; tl = t - F2; }
        else                  { w = w4; K = 128; N = 38;  KC = 4;  base = W4P; tl = t - F2 - F3; }
        const int ct  = tl / KC;
        const int kc  = tl - ct * KC;
        const int col = ct * 16 + (lane & 15);
        const int k0  = kc * 32 + (lane >> 4) * 8;
        unsigned short o8[8];
        #pragma unroll
        for (int e = 0; e < 8; ++e)
            o8[e] = (col < N) ? (unsigned short)f2bf(w[col * K + k0 + e]) : (unsigned short)0;
        *reinterpret_cast<s16x8*>(dst + base + (size_t)(tl * 64 + lane) * 8) =
            *reinterpret_cast<s16x8*>(o8);
    }
}

// prep2: pair tables from fp32 GF; block (va,vb) writes P01[va,vb] AND P34[va,vb]
__global__ void prep2(const float* __restrict__ b1, unsigned short* __restrict__ dst) {
    const float* gf = reinterpret_cast<const float*>(dst + BF_END);
    const int o   = threadIdx.x;
    const int bid = blockIdx.x;
    if (bid < 1521) {
        const int va = bid / 39, vb = bid % 39;
        dst[P01P + bid * 512 + o] =
            bfbits(b1[o] + gf[(0 * 39 + va) * 512 + o] + gf[(1 * 39 + vb) * 512 + o]);
        dst[P34P + bid * 512 + o] =
            bfbits(gf[(3 * 39 + va) * 512 + o] + gf[(4 * 39 + vb) * 512 + o]);
    } else {
        const int v = bid - 1521;
        dst[G2P + v * 512 + o] = bfbits(gf[(2 * 39 + v) * 512 + o]);
    }
}

// LDS (64.5 KB, 512 threads, M=64, 2 blocks/CU):
//   buf A @ 0     (32768): h1a (64 x 256 cols, stride 512B) -> h2 (64 x 256, stride 512B)
//   buf B @ 32768 (32768): h1b (64 x 256, stride 512B)      -> h3 (64 x 128, stride 256B)
//   tok  @ 65536  (68 ints)
#define BA 0
#define BB 32768
#define TOKO 65536

#define SWZ(b, row) ((b) ^ (((row) & 15) << 4))

__device__ __forceinline__ u32x2 pack_relu(f32x4 a, float4 b) {
    u32x2 r;
    r[0] = pk2(fmaxf(a[0] + b.x, 0.f), fmaxf(a[1] + b.y, 0.f));
    r[1] = pk2(fmaxf(a[2] + b.z, 0.f), fmaxf(a[3] + b.w, 0.f));
    return r;
}

__launch_bounds__(512, 4)
__global__ void fused_mlp(const int* __restrict__ tok,
                          const unsigned short* __restrict__ wbf,
                          const float* __restrict__ b2,
                          const float* __restrict__ b3,
                          const float* __restrict__ b4,
                          float* __restrict__ out) {
    __shared__ char smem[65536 + 512];
    const int tid  = threadIdx.x;
    const int lane = tid & 63;
    const int wave = tid >> 6;                 // 0..7
    const int l15  = lane & 15;
    const int l4   = lane >> 4;                // 0..3
    const int r0   = blockIdx.x * 64;
    const int s0   = r0 & (SEQ - 1);
    const int bat  = r0 >> 10;

    int* tokL = reinterpret_cast<int*>(smem + TOKO);

    // ---------- stage context tokens (OOB -> 38, the zero table row)
    if (tid < 68) {
        const int sp = s0 - 2 + tid;
        tokL[tid] = (sp >= 0 && sp < SEQ) ? tok[bat * SEQ + sp] : 38;
    }
    __syncthreads();

    // per-thread phase-1 assignment: row = tid>>3, 8 threads cover 256 dims per half
    const int p1row = tid >> 3;
    const int p1c   = tid & 7;
    int off01, off2, off34;
    {
        const int t0 = tokL[p1row],     t1 = tokL[p1row + 1], t2 = tokL[p1row + 2];
        const int t3 = tokL[p1row + 3], t4 = tokL[p1row + 4];
        off01 = (t0 * 39 + t1) * 512;
        off2  = t2 * 512;
        off34 = (t3 * 39 + t4) * 512;
    }

    // ---------- phase 1a: h1 dims [0,256) -> buf A
    #pragma unroll
    for (int it = 0; it < 4; ++it) {
        const int c8 = it * 8 + p1c;           // 0..31 (8-dim chunk within half)
        const int d  = c8 * 8;                 // dim offset within half
        const s16x8 va = *reinterpret_cast<const s16x8*>(wbf + P01P + off01 + d);
        const s16x8 vb = *reinterpret_cast<const s16x8*>(wbf + G2P  + off2  + d);
        const s16x8 vc = *reinterpret_cast<const s16x8*>(wbf + P34P + off34 + d);
        u32x4 wv;
        #pragma unroll
        for (int h = 0; h < 4; ++h) {
            const float e0 = bf2f(va[2 * h])     + bf2f(vb[2 * h])     + bf2f(vc[2 * h]);
            const float e1 = bf2f(va[2 * h + 1]) + bf2f(vb[2 * h + 1]) + bf2f(vc[2 * h + 1]);
            wv[h] = pk2(fmaxf(e0, 0.f), fmaxf(e1, 0.f));
        }
        *reinterpret_cast<u32x4*>(smem + BA + SWZ(p1row * 512 + c8 * 16, p1row)) = wv;
    }
    __syncthreads();

    // ---------- GEMM2 part A (ks 0..7, reads buf A) + phase 1b (dims [256,512) -> buf B)
    f32x4 acc2[4][2];
    #pragma unroll
    for (int rt = 0; rt < 4; ++rt)
        #pragma unroll
        for (int ct = 0; ct < 2; ++ct) acc2[rt][ct] = (f32x4){0.f, 0.f, 0.f, 0.f};
    {
        // phase 1b loads are independent of GEMM2-A; compiler may hoist them
        #pragma unroll
        for (int it = 0; it < 4; ++it) {
            const int c8 = it * 8 + p1c;
            const int d  = 256 + c8 * 8;
            const s16x8 va = *reinterpret_cast<const s16x8*>(wbf + P01P + off01 + d);
            const s16x8 vb = *reinterpret_cast<const s16x8*>(wbf + G2P  + off2  + d);
            const s16x8 vc = *reinterpret_cast<const s16x8*>(wbf + P34P + off34 + d);
            u32x4 wv;
            #pragma unroll
            for (int h = 0; h < 4; ++h) {
                const float e0 = bf2f(va[2 * h])     + bf2f(vb[2 * h])     + bf2f(vc[2 * h]);
                const float e1 = bf2f(va[2 * h + 1]) + bf2f(vb[2 * h + 1]) + bf2f(vc[2 * h + 1]);
                wv[h] = pk2(fmaxf(e0, 0.f), fmaxf(e1, 0.f));
            }
            *reinterpret_cast<u32x4*>(smem + BB + SWZ(p1row * 512 + c8 * 16, p1row)) = wv;
        }
        for (int ks = 0; ks < 8; ++ks) {
            s16x8 xv[4];
            #pragma unroll
            for (int rt = 0; rt < 4; ++rt) {
                const int row = rt * 16 + l15;
                xv[rt] = *reinterpret_cast<const s16x8*>(
                    smem + BA + SWZ(row * 512 + ks * 64 + l4 * 16, row));
            }
            #pragma unroll
            for (int ct = 0; ct < 2; ++ct) {
                const s16x8 w = *reinterpret_cast<const s16x8*>(
                    wbf + W2P + (((wave * 2 + ct) * 16 + ks) * 64 + lane) * 8);
                #pragma unroll
                for (int rt = 0; rt < 4; ++rt)
                    acc2[rt][ct] = __builtin_amdgcn_mfma_f32_16x16x32_bf16(w, xv[rt], acc2[rt][ct], 0, 0, 0);
            }
        }
    }
    __syncthreads();

    // ---------- GEMM2 part B (ks 8..15, reads buf B) + epilogue -> h2 in buf A
    {
        for (int ks = 0; ks < 8; ++ks) {
            s16x8 xv[4];
            #pragma unroll
            for (int rt = 0; rt < 4; ++rt) {
                const int row = rt * 16 + l15;
                xv[rt] = *reinterpret_cast<const s16x8*>(
                    smem + BB + SWZ(row * 512 + ks * 64 + l4 * 16, row));
            }
            #pragma unroll
            for (int ct = 0; ct < 2; ++ct) {
                const s16x8 w = *reinterpret_cast<const s16x8*>(
                    wbf + W2P + (((wave * 2 + ct) * 16 + 8 + ks) * 64 + lane) * 8);
                #pragma unroll
                for (int rt = 0; rt < 4; ++rt)
                    acc2[rt][ct] = __builtin_amdgcn_mfma_f32_16x16x32_bf16(w, xv[rt], acc2[rt][ct], 0, 0, 0);
            }
        }
        #pragma unroll
        for (int ct = 0; ct < 2; ++ct) {
            const int col0 = (wave * 2 + ct) * 16 + l4 * 4;
            const float4 bb = *reinterpret_cast<const float4*>(b2 + col0);
            #pragma unroll
            for (int rt = 0; rt < 4; ++rt) {
                const int row = rt * 16 + l15;
                *reinterpret_cast<u32x2*>(smem + BA + SWZ(row * 512 + col0 * 2, row)) =
                    pack_relu(acc2[rt][ct], bb);
            }
        }
    }
    __syncthreads();

    // ---------- GEMM3 (swapped): [64,256] -> [64,128]; wave owns ctile=wave x 4 row-tiles
    {
        f32x4 acc[4];
        #pragma unroll
        for (int rt = 0; rt < 4; ++rt) acc[rt] = (f32x4){0.f, 0.f, 0.f, 0.f};
        for (int ks = 0; ks < 8; ++ks) {
            const s16x8 w = *reinterpret_cast<const s16x8*>(
                wbf + W3P + ((wave * 8 + ks) * 64 + lane) * 8);
            #pragma unroll
            for (int rt = 0; rt < 4; ++rt) {
                const int row = rt * 16 + l15;
                const s16x8 xv = *reinterpret_cast<const s16x8*>(
                    smem + BA + SWZ(row * 512 + ks * 64 + l4 * 16, row));
                acc[rt] = __builtin_amdgcn_mfma_f32_16x16x32_bf16(w, xv, acc[rt], 0, 0, 0);
            }
        }
        const int col0 = wave * 16 + l4 * 4;
        const float4 bb = *reinterpret_cast<const float4*>(b3 + col0);
        #pragma unroll
        for (int rt = 0; rt < 4; ++rt) {
            const int row = rt * 16 + l15;
            *reinterpret_cast<u32x2*>(smem + BB + SWZ(row * 256 + col0 * 2, row)) =
                pack_relu(acc[rt], bb);
        }
    }
    __syncthreads();

    // ---------- GEMM4 (swapped): [64,128] -> out[64,38]; 12 tasks over 8 waves
    for (int task = wave; task < 12; task += 8) {
        const int mt = task >> 2;              // W4 col tile 0..2
        const int rt = task & 3;               // row tile 0..3
        f32x4 acc = (f32x4){0.f, 0.f, 0.f, 0.f};
        #pragma unroll
        for (int ks = 0; ks < 4; ++ks) {
            const int row = rt * 16 + l15;
            const s16x8 xv = *reinterpret_cast<const s16x8*>(
                smem + BB + SWZ(row * 256 + ks * 64 + l4 * 16, row));
            const s16x8 w = *reinterpret_cast<const s16x8*>(
                wbf + W4P + ((mt * 4 + ks) * 64 + lane) * 8);
            acc = __builtin_amdgcn_mfma_f32_16x16x32_bf16(w, xv, acc, 0, 0, 0);
        }
        const int rg   = r0 + rt * 16 + l15;
        const int col0 = mt * 16 + l4 * 4;
        #pragma unroll
        for (int h = 0; h < 2; ++h) {
            const int c = col0 + 2 * h;
            if (c < 38) {
                f32x2 v;
                v[0] = acc[2 * h]     + b4[c];
                v[1] = acc[2 * h + 1] + b4[c + 1];
                *reinterpret_cast<f32x2*>(out + rg * 38 + c) = v;
            }
        }
    }
}

extern "C" void kernel_launch(void* const* d_in, const int* in_sizes, int n_in,
                              void* d_out, int out_size, void* d_ws, size_t ws_size,
                              hipStream_t stream) {
    const int*   tok = (const int*)d_in[0];
    const float* emb = (const float*)d_in[1];
    const float* W1  = (const float*)d_in[2];
    const float* b1  = (const float*)d_in[3];
    const float* W2  = (const float*)d_in[4];
    const float* b2  = (const float*)d_in[5];
    const float* W3  = (const float*)d_in[6];
    const float* b3  = (const float*)d_in[7];
    const float* W4  = (const float*)d_in[8];
    const float* b4  = (const float*)d_in[9];
    float* out = (float*)d_out;
    unsigned short* wbf = (unsigned short*)d_ws;

    const int pack_blocks = (FTOT * 64 + 511) / 512;     // 42
    prep1<<<195 + pack_blocks, 512, 0, stream>>>(W1, W2, W3, W4, emb, wbf);
    prep2<<<1521 + 39, 512, 0, stream>>>(b1, wbf);
    fused_mlp<<<1024, 512, 0, stream>>>(tok, wbf, b2, b3, b4, out);
}